// Round 6
// baseline (1829.722 us; speedup 1.0000x reference)
//
#include <hip/hip_runtime.h>
#include <math.h>
#include <stdint.h>

// ---------------- constants ----------------
#define BATCH 16
#define SLEN  192
#define DMODEL 512
#define UIN   258
#define NTOK  (BATCH*SLEN)      // 3072
#define NLAY  4

// ---------------- positional encoding table (16 x 512) ----------------
__global__ void pe_k(float* __restrict__ pe) {
    int b = blockIdx.x;          // 0..15
    int i = threadIdx.x;         // 0..255
    float div = expf((float)(2 * i) * (-9.210340371976184f / 512.0f));
    float a = (float)b * div;
    pe[b * 512 + 2 * i]     = sinf(a);
    pe[b * 512 + 2 * i + 1] = cosf(a);
}

// ---------------- embed + PE ----------------
__global__ __launch_bounds__(256) void embed_k(
    const float* __restrict__ src, const float* __restrict__ wemb,
    const float* __restrict__ semb, const float* __restrict__ pe,
    float* __restrict__ x)
{
    int n = blockIdx.x;                 // token
    int b = n / SLEN;
    int t = threadIdx.x;
    int wi = (int)src[(size_t)n * UIN + 256];
    int si = (int)src[(size_t)n * UIN + 257];
    float v0 = src[(size_t)n * UIN + t];
    x[(size_t)n * 512 + t] = v0 + pe[b * 512 + t];
    int d = t + 256;
    float v1 = (d < 384) ? wemb[(size_t)wi * 128 + (d - 256)]
                         : semb[(size_t)si * 128 + (d - 384)];
    x[(size_t)n * 512 + d] = v1 + pe[b * 512 + d];
}

// ---------------- generic 64x64 tiled GEMM: C = alpha*A@op(B) + bias ----------------
template <bool BT>
__global__ __launch_bounds__(256) void gemm64(
    const float* __restrict__ A, int lda, long long sAb, long long sAh,
    const float* __restrict__ B, int ldb, long long sBb, long long sBh,
    float* __restrict__ C, int ldc, long long sCb, long long sCh,
    int K, const float* __restrict__ bias, float alpha, int nh)
{
    int z = blockIdx.z;
    int zb = z / nh, zh = z - zb * nh;
    A += (size_t)zb * sAb + (size_t)zh * sAh;
    B += (size_t)zb * sBb + (size_t)zh * sBh;
    C += (size_t)zb * sCb + (size_t)zh * sCh;

    __shared__ float As[16][68];
    __shared__ float Bs[16][68];

    int t = threadIdx.x;
    int row0 = blockIdx.x * 64, col0 = blockIdx.y * 64;
    int lr = t >> 2, lk = (t & 3) << 2;
    int brow = t >> 4, bcol = (t & 15) << 2;
    int ty = (t >> 4) << 2, tx = (t & 15) << 2;

    float acc[4][4] = {};

    for (int k0 = 0; k0 < K; k0 += 16) {
        float4 a4 = *(const float4*)(A + (size_t)(row0 + lr) * lda + k0 + lk);
        As[lk][lr] = a4.x; As[lk + 1][lr] = a4.y; As[lk + 2][lr] = a4.z; As[lk + 3][lr] = a4.w;
        if (BT) {
            float4 b4 = *(const float4*)(B + (size_t)(col0 + lr) * ldb + k0 + lk);
            Bs[lk][lr] = b4.x; Bs[lk + 1][lr] = b4.y; Bs[lk + 2][lr] = b4.z; Bs[lk + 3][lr] = b4.w;
        } else {
            float4 b4 = *(const float4*)(B + (size_t)(k0 + brow) * ldb + col0 + bcol);
            *(float4*)&Bs[brow][bcol] = b4;
        }
        __syncthreads();
#pragma unroll
        for (int k = 0; k < 16; ++k) {
            const float4 av = *(const float4*)&As[k][ty];
            const float4 bv = *(const float4*)&Bs[k][tx];
            acc[0][0] += av.x * bv.x; acc[0][1] += av.x * bv.y; acc[0][2] += av.x * bv.z; acc[0][3] += av.x * bv.w;
            acc[1][0] += av.y * bv.x; acc[1][1] += av.y * bv.y; acc[1][2] += av.y * bv.z; acc[1][3] += av.y * bv.w;
            acc[2][0] += av.z * bv.x; acc[2][1] += av.z * bv.y; acc[2][2] += av.z * bv.z; acc[2][3] += av.z * bv.w;
            acc[3][0] += av.w * bv.x; acc[3][1] += av.w * bv.y; acc[3][2] += av.w * bv.z; acc[3][3] += av.w * bv.w;
        }
        __syncthreads();
    }
#pragma unroll
    for (int i2 = 0; i2 < 4; ++i2) {
        size_t crow = (size_t)(row0 + ty + i2) * ldc + col0 + tx;
#pragma unroll
        for (int j = 0; j < 4; ++j) {
            float v = alpha * acc[i2][j];
            if (bias) v += bias[col0 + tx + j];
            C[crow + j] = v;
        }
    }
}

// ---------------- encoder softmax: rows of 192, 1 wave per row ----------------
__global__ __launch_bounds__(256) void enc_softmax(float* __restrict__ scores) {
    int row = blockIdx.x * 4 + (threadIdx.x >> 6);
    int lane = threadIdx.x & 63;
    float* p = scores + (size_t)row * 192;
    float v0 = p[lane], v1 = p[lane + 64], v2 = p[lane + 128];
    float m = fmaxf(fmaxf(v0, v1), v2);
#pragma unroll
    for (int s = 1; s < 64; s <<= 1) m = fmaxf(m, __shfl_xor(m, s));
    float e0 = __expf(v0 - m), e1 = __expf(v1 - m), e2 = __expf(v2 - m);
    float sm = e0 + e1 + e2;
#pragma unroll
    for (int s = 1; s < 64; s <<= 1) sm += __shfl_xor(sm, s);
    float r = 1.0f / sm;
    p[lane] = e0 * r; p[lane + 64] = e1 * r; p[lane + 128] = e2 * r;
}

// ---------------- residual + LN (512) ----------------
__global__ __launch_bounds__(256) void res_ln(
    float* __restrict__ x, const float* __restrict__ y,
    const float* __restrict__ g, const float* __restrict__ bb)
{
    int n = blockIdx.x, t = threadIdx.x, wave = t >> 6, lane = t & 63;
    __shared__ float red[16];
    size_t base = (size_t)n * 512;
    float z0 = x[base + t] + y[base + t];
    float z1 = x[base + t + 256] + y[base + t + 256];
    float s = z0 + z1, sq = z0 * z0 + z1 * z1;
#pragma unroll
    for (int m = 1; m < 64; m <<= 1) { s += __shfl_xor(s, m); sq += __shfl_xor(sq, m); }
    if (lane == 0) { red[wave] = s; red[8 + wave] = sq; }
    __syncthreads();
    if (t == 0) {
        float S = red[0] + red[1] + red[2] + red[3];
        float Q = red[8] + red[9] + red[10] + red[11];
        float mean = S * (1.0f / 512.0f);
        float var = Q * (1.0f / 512.0f) - mean * mean;
        red[0] = mean; red[1] = 1.0f / sqrtf(var + 1e-5f);
    }
    __syncthreads();
    float mean = red[0], rs = red[1];
    x[base + t]       = (z0 - mean) * rs * g[t] + bb[t];
    x[base + t + 256] = (z1 - mean) * rs * g[t + 256] + bb[t + 256];
}

// ---------------- fused FFN (512->4 relu ->512) + residual + LN ----------------
__global__ __launch_bounds__(256) void enc_ffn_ln(
    float* __restrict__ x,
    const float* __restrict__ w1, const float* __restrict__ b1,
    const float* __restrict__ w2, const float* __restrict__ b2,
    const float* __restrict__ g, const float* __restrict__ bb)
{
    int n = blockIdx.x, t = threadIdx.x, wave = t >> 6, lane = t & 63;
    __shared__ float xs[512];
    __shared__ float hs[4];
    __shared__ float red[16];
    size_t base = (size_t)n * 512;
    float x0 = x[base + t], x1 = x[base + t + 256];
    xs[t] = x0; xs[t + 256] = x1;
    __syncthreads();
    float p = 0.0f;
    for (int c = lane; c < 512; c += 64) p += xs[c] * w1[wave * 512 + c];
#pragma unroll
    for (int m = 1; m < 64; m <<= 1) p += __shfl_xor(p, m);
    if (lane == 0) hs[wave] = fmaxf(p + b1[wave], 0.0f);
    __syncthreads();
    float h0 = hs[0], h1 = hs[1], h2 = hs[2], h3 = hs[3];
    int t2 = t + 256;
    float z0 = x0 + b2[t]  + h0 * w2[t * 4]  + h1 * w2[t * 4 + 1]  + h2 * w2[t * 4 + 2]  + h3 * w2[t * 4 + 3];
    float z1 = x1 + b2[t2] + h0 * w2[t2 * 4] + h1 * w2[t2 * 4 + 1] + h2 * w2[t2 * 4 + 2] + h3 * w2[t2 * 4 + 3];
    float s = z0 + z1, sq = z0 * z0 + z1 * z1;
#pragma unroll
    for (int m = 1; m < 64; m <<= 1) { s += __shfl_xor(s, m); sq += __shfl_xor(sq, m); }
    if (lane == 0) { red[wave] = s; red[8 + wave] = sq; }
    __syncthreads();
    if (t == 0) {
        float S = red[0] + red[1] + red[2] + red[3];
        float Q = red[8] + red[9] + red[10] + red[11];
        float mean = S * (1.0f / 512.0f);
        float var = Q * (1.0f / 512.0f) - mean * mean;
        red[0] = mean; red[1] = 1.0f / sqrtf(var + 1e-5f);
    }
    __syncthreads();
    float mean = red[0], rs = red[1];
    x[base + t]  = (z0 - mean) * rs * g[t]  + bb[t];
    x[base + t2] = (z1 - mean) * rs * g[t2] + bb[t2];
}

// ---------------- final LN + eout projection (512->3) + copy index cols ----------------
__global__ __launch_bounds__(256) void eout_k(
    const float* __restrict__ x,
    const float* __restrict__ g, const float* __restrict__ bb,
    const float* __restrict__ ew, const float* __restrict__ eb,
    const float* __restrict__ src, float* __restrict__ mem, float* __restrict__ out)
{
    int n = blockIdx.x, t = threadIdx.x, wave = t >> 6, lane = t & 63;
    __shared__ float xs[512];
    __shared__ float red[16];
    size_t base = (size_t)n * 512;
    float z0 = x[base + t], z1 = x[base + t + 256];
    float s = z0 + z1, sq = z0 * z0 + z1 * z1;
#pragma unroll
    for (int m = 1; m < 64; m <<= 1) { s += __shfl_xor(s, m); sq += __shfl_xor(sq, m); }
    if (lane == 0) { red[wave] = s; red[8 + wave] = sq; }
    __syncthreads();
    if (t == 0) {
        float S = red[0] + red[1] + red[2] + red[3];
        float Q = red[8] + red[9] + red[10] + red[11];
        float mean = S * (1.0f / 512.0f);
        float var = Q * (1.0f / 512.0f) - mean * mean;
        red[0] = mean; red[1] = 1.0f / sqrtf(var + 1e-5f);
    }
    __syncthreads();
    float mean = red[0], rs = red[1];
    xs[t]       = (z0 - mean) * rs * g[t] + bb[t];
    xs[t + 256] = (z1 - mean) * rs * g[t + 256] + bb[t + 256];
    __syncthreads();
    if (wave < 3) {
        float p = 0.0f;
        for (int c = lane; c < 512; c += 64) p += xs[c] * ew[wave * 512 + c];
#pragma unroll
        for (int m = 1; m < 64; m <<= 1) p += __shfl_xor(p, m);
        if (lane == 0) mem[(size_t)n * 3 + wave] = p + eb[wave];
    }
    if (t == 0) {
        out[(size_t)n * 5 + 3] = src[(size_t)n * UIN + 256];
        out[(size_t)n * 5 + 4] = src[(size_t)n * UIN + 257];
    }
}

// ---------------- precompute cross-attention K/V of memory per layer ----------------
// layout: kmem[b][l][s][3]
__global__ __launch_bounds__(256) void crosskv_k(
    const float* __restrict__ mem, const float* __restrict__ w, const float* __restrict__ bias,
    float* __restrict__ kmem, float* __restrict__ vmem)
{
    int idx = blockIdx.x * 256 + threadIdx.x;   // < 16*4*192
    int s = idx % SLEN;
    int l = (idx / SLEN) & 3;
    int b = idx / (SLEN * 4);
    const float* m = mem + ((size_t)b * SLEN + s) * 3;
    float m0 = m[0], m1 = m[1], m2 = m[2];
    const float* wl = w + l * 27;
    const float* bl = bias + l * 9;
    float* kp = kmem + (size_t)idx * 3;
    float* vp = vmem + (size_t)idx * 3;
#pragma unroll
    for (int r = 0; r < 3; ++r) {
        kp[r] = wl[(3 + r) * 3] * m0 + wl[(3 + r) * 3 + 1] * m1 + wl[(3 + r) * 3 + 2] * m2 + bl[3 + r];
        vp[r] = wl[(6 + r) * 3] * m0 + wl[(6 + r) * 3 + 1] * m1 + wl[(6 + r) * 3 + 2] * m2 + bl[6 + r];
    }
}

// ---------------- DPP wave-64 sum reduce (VALU latency, no LDS pipe) ----------------
// row_shr:1/2/4/8 then row_bcast:15, row_bcast:31; total lands in lane 63.
template <int CTRL>
__device__ __forceinline__ float dpp_add(float x) {
    int s = __builtin_amdgcn_update_dpp(0, __float_as_int(x), CTRL, 0xf, 0xf, true);
    return x + __int_as_float(s);
}
__device__ __forceinline__ float wave_sum64(float x) {
    x = dpp_add<0x111>(x);   // row_shr:1
    x = dpp_add<0x112>(x);   // row_shr:2
    x = dpp_add<0x114>(x);   // row_shr:4
    x = dpp_add<0x118>(x);   // row_shr:8
    x = dpp_add<0x142>(x);   // row_bcast:15
    x = dpp_add<0x143>(x);   // row_bcast:31
    return __int_as_float(__builtin_amdgcn_readlane(__float_as_int(x), 63));
}

// Opaque identity: pins a value into a VGPR and makes it impossible for the
// compiler to rematerialize the original load. (R4 evidence: VGPR_Count=92 <
// 144 cache floats => LLVM was re-loading Km/Vm from global every layer.)
#define PIN(x) asm volatile("" : "+v"(x))

// ---------------- autoregressive decoder: 1 block (1 wave) per batch ----------------
// All K/V caches live in per-lane REGISTERS (lane j owns positions j, j+64, j+128).
// Weights read straight from global (wave-uniform addresses -> scalar s_load pipe).
// Zero LDS, zero barriers inside the AR loop.
__global__ __launch_bounds__(64, 1) void decoder_ar(
    const float* __restrict__ kmem, const float* __restrict__ vmem,
    const float* __restrict__ sa_qkv_w, const float* __restrict__ sa_qkv_b,
    const float* __restrict__ sa_o_w, const float* __restrict__ sa_o_b,
    const float* __restrict__ ca_qkv_w, const float* __restrict__ ca_qkv_b,
    const float* __restrict__ ca_o_w, const float* __restrict__ ca_o_b,
    const float* __restrict__ ln1g, const float* __restrict__ ln1b,
    const float* __restrict__ ln2g, const float* __restrict__ ln2b,
    const float* __restrict__ ln3g, const float* __restrict__ ln3b,
    const float* __restrict__ f1w, const float* __restrict__ f1b,
    const float* __restrict__ f2w, const float* __restrict__ f2b,
    float* __restrict__ out)
{
    int b = blockIdx.x, lane = threadIdx.x;
    const float isc = 0.57735026918962576f;   // 1/sqrt(3)

    // cross-attn K/V: [layer][slot][comp], slot s = position s*64+lane
    float Km[4][3][3], Vm[4][3][3];
#pragma unroll
    for (int l = 0; l < 4; ++l)
#pragma unroll
        for (int s = 0; s < 3; ++s) {
            size_t base = (((size_t)(b * 4 + l)) * SLEN + s * 64 + lane) * 3;
#pragma unroll
            for (int r = 0; r < 3; ++r) {
                Km[l][s][r] = kmem[base + r];
                Vm[l][s][r] = vmem[base + r];
            }
        }
    // Pin the caches in VGPRs (defeat load rematerialization).
#pragma unroll
    for (int l = 0; l < 4; ++l)
#pragma unroll
        for (int s = 0; s < 3; ++s)
#pragma unroll
            for (int r = 0; r < 3; ++r) { PIN(Km[l][s][r]); PIN(Vm[l][s][r]); }

    // self-attn K/V cache in registers, same lane->position mapping
    float Kc[4][3][3], Vc[4][3][3];
#pragma unroll
    for (int l = 0; l < 4; ++l)
#pragma unroll
        for (int s = 0; s < 3; ++s)
#pragma unroll
            for (int r = 0; r < 3; ++r) { Kc[l][s][r] = 0.0f; Vc[l][s][r] = 0.0f; }

    if (lane < 3) out[(size_t)(b * SLEN) * 5 + lane] = 0.0f;   // tgt[b,0,:] = 0

    float y0 = 0.0f, y1 = 0.0f, y2 = 0.0f;

    for (int i = 0; i < SLEN - 1; ++i) {
        int slot = i >> 6;          // wave-uniform
        int tl = i & 63;
#pragma unroll
        for (int l = 0; l < 4; ++l) {
            // --- self-attention: QKV proj (replicated in all lanes; weights via s_load) ---
            const float* W = sa_qkv_w + l * 27;
            const float* Bw = sa_qkv_b + l * 9;
            float q[3], k[3], v[3];
#pragma unroll
            for (int r = 0; r < 3; ++r) {
                q[r] = (W[r * 3] * y0 + W[r * 3 + 1] * y1 + W[r * 3 + 2] * y2 + Bw[r]) * isc;
                k[r] = W[(3 + r) * 3] * y0 + W[(3 + r) * 3 + 1] * y1 + W[(3 + r) * 3 + 2] * y2 + Bw[3 + r];
                v[r] = W[(6 + r) * 3] * y0 + W[(6 + r) * 3 + 1] * y1 + W[(6 + r) * 3 + 2] * y2 + Bw[6 + r];
            }
            // store position i into the owning lane's registers
            bool mine = (lane == tl);
            if (slot == 0) {
                if (mine) {
#pragma unroll
                    for (int r = 0; r < 3; ++r) { Kc[l][0][r] = k[r]; Vc[l][0][r] = v[r]; }
                }
            } else if (slot == 1) {
                if (mine) {
#pragma unroll
                    for (int r = 0; r < 3; ++r) { Kc[l][1][r] = k[r]; Vc[l][1][r] = v[r]; }
                }
            } else {
                if (mine) {
#pragma unroll
                    for (int r = 0; r < 3; ++r) { Kc[l][2][r] = k[r]; Vc[l][2][r] = v[r]; }
                }
            }
            // attend over positions 0..i (register reads only, per-lane slots)
            float den = 0.0f, a0 = 0.0f, a1 = 0.0f, a2 = 0.0f;
#pragma unroll
            for (int s = 0; s < 3; ++s) {
                int pos = (s << 6) + lane;
                float sc = q[0] * Kc[l][s][0] + q[1] * Kc[l][s][1] + q[2] * Kc[l][s][2];
                float e = (pos <= i) ? __expf(sc) : 0.0f;
                den += e; a0 += e * Vc[l][s][0]; a1 += e * Vc[l][s][1]; a2 += e * Vc[l][s][2];
            }
            den = wave_sum64(den); a0 = wave_sum64(a0); a1 = wave_sum64(a1); a2 = wave_sum64(a2);
            float ri = 1.0f / den;
            float o0 = a0 * ri, o1 = a1 * ri, o2 = a2 * ri;
            const float* Ow = sa_o_w + l * 9;
            const float* Ob = sa_o_b + l * 3;
            y0 += Ow[0] * o0 + Ow[1] * o1 + Ow[2] * o2 + Ob[0];
            y1 += Ow[3] * o0 + Ow[4] * o1 + Ow[5] * o2 + Ob[1];
            y2 += Ow[6] * o0 + Ow[7] * o1 + Ow[8] * o2 + Ob[2];
            {   // LN1
                const float* G = ln1g + l * 3; const float* Bb = ln1b + l * 3;
                float mn = (y0 + y1 + y2) * (1.0f / 3.0f);
                float d0 = y0 - mn, d1 = y1 - mn, d2 = y2 - mn;
                float rs = 1.0f / sqrtf((d0 * d0 + d1 * d1 + d2 * d2) * (1.0f / 3.0f) + 1e-5f);
                y0 = d0 * rs * G[0] + Bb[0]; y1 = d1 * rs * G[1] + Bb[1]; y2 = d2 * rs * G[2] + Bb[2];
            }
            // --- cross-attention ---
            const float* Cw = ca_qkv_w + l * 27;
            const float* Cb = ca_qkv_b + l * 9;
            float c0 = (Cw[0] * y0 + Cw[1] * y1 + Cw[2] * y2 + Cb[0]) * isc;
            float c1 = (Cw[3] * y0 + Cw[4] * y1 + Cw[5] * y2 + Cb[1]) * isc;
            float c2 = (Cw[6] * y0 + Cw[7] * y1 + Cw[8] * y2 + Cb[2]) * isc;
            den = 0.0f; a0 = 0.0f; a1 = 0.0f; a2 = 0.0f;
#pragma unroll
            for (int s = 0; s < 3; ++s) {
                float sc = c0 * Km[l][s][0] + c1 * Km[l][s][1] + c2 * Km[l][s][2];
                float e = __expf(sc);
                den += e; a0 += e * Vm[l][s][0]; a1 += e * Vm[l][s][1]; a2 += e * Vm[l][s][2];
            }
            den = wave_sum64(den); a0 = wave_sum64(a0); a1 = wave_sum64(a1); a2 = wave_sum64(a2);
            ri = 1.0f / den;
            o0 = a0 * ri; o1 = a1 * ri; o2 = a2 * ri;
            const float* Co = ca_o_w + l * 9;
            const float* Cob = ca_o_b + l * 3;
            y0 += Co[0] * o0 + Co[1] * o1 + Co[2] * o2 + Cob[0];
            y1 += Co[3] * o0 + Co[4] * o1 + Co[5] * o2 + Cob[1];
            y2 += Co[6] * o0 + Co[7] * o1 + Co[8] * o2 + Cob[2];
            {   // LN2
                const float* G = ln2g + l * 3; const float* Bb = ln2b + l * 3;
                float mn = (y0 + y1 + y2) * (1.0f / 3.0f);
                float d0 = y0 - mn, d1 = y1 - mn, d2 = y2 - mn;
                float rs = 1.0f / sqrtf((d0 * d0 + d1 * d1 + d2 * d2) * (1.0f / 3.0f) + 1e-5f);
                y0 = d0 * rs * G[0] + Bb[0]; y1 = d1 * rs * G[1] + Bb[1]; y2 = d2 * rs * G[2] + Bb[2];
            }
            // --- FFN 3->4 relu ->3 ---
            const float* F1 = f1w + l * 12; const float* FB1 = f1b + l * 4;
            const float* F2 = f2w + l * 12; const float* FB2 = f2b + l * 3;
            float h0 = fmaxf(F1[0] * y0 + F1[1]  * y1 + F1[2]  * y2 + FB1[0], 0.0f);
            float h1 = fmaxf(F1[3] * y0 + F1[4]  * y1 + F1[5]  * y2 + FB1[1], 0.0f);
            float h2 = fmaxf(F1[6] * y0 + F1[7]  * y1 + F1[8]  * y2 + FB1[2], 0.0f);
            float h3 = fmaxf(F1[9] * y0 + F1[10] * y1 + F1[11] * y2 + FB1[3], 0.0f);
            y0 += F2[0] * h0 + F2[1] * h1 + F2[2]  * h2 + F2[3]  * h3 + FB2[0];
            y1 += F2[4] * h0 + F2[5] * h1 + F2[6]  * h2 + F2[7]  * h3 + FB2[1];
            y2 += F2[8] * h0 + F2[9] * h1 + F2[10] * h2 + F2[11] * h3 + FB2[2];
            {   // LN3
                const float* G = ln3g + l * 3; const float* Bb = ln3b + l * 3;
                float mn = (y0 + y1 + y2) * (1.0f / 3.0f);
                float d0 = y0 - mn, d1 = y1 - mn, d2 = y2 - mn;
                float rs = 1.0f / sqrtf((d0 * d0 + d1 * d1 + d2 * d2) * (1.0f / 3.0f) + 1e-5f);
                y0 = d0 * rs * G[0] + Bb[0]; y1 = d1 * rs * G[1] + Bb[1]; y2 = d2 * rs * G[2] + Bb[2];
            }
        }
        if (lane == 0) {
            size_t o = (size_t)(b * SLEN + i + 1) * 5;
            out[o] = y0; out[o + 1] = y1; out[o + 2] = y2;
        }
    }
}

// ---------------- host launcher ----------------
extern "C" void kernel_launch(void* const* d_in, const int* in_sizes, int n_in,
                              void* d_out, int out_size, void* d_ws, size_t ws_size,
                              hipStream_t stream)
{
    const float* src   = (const float*)d_in[0];
    const float* wemb  = (const float*)d_in[1];
    const float* semb  = (const float*)d_in[2];
    const float* eqkvw = (const float*)d_in[3];
    const float* eqkvb = (const float*)d_in[4];
    const float* eow   = (const float*)d_in[5];
    const float* eob   = (const float*)d_in[6];
    const float* eln1g = (const float*)d_in[7];
    const float* eln1b = (const float*)d_in[8];
    const float* ef1w  = (const float*)d_in[9];
    const float* ef1b  = (const float*)d_in[10];
    const float* ef2w  = (const float*)d_in[11];
    const float* ef2b  = (const float*)d_in[12];
    const float* eln2g = (const float*)d_in[13];
    const float* eln2b = (const float*)d_in[14];
    const float* nfg   = (const float*)d_in[15];
    const float* nfb   = (const float*)d_in[16];
    const float* eoutw = (const float*)d_in[17];
    const float* eoutb = (const float*)d_in[18];
    const float* dsaqw = (const float*)d_in[19];
    const float* dsaqb = (const float*)d_in[20];
    const float* dsaow = (const float*)d_in[21];
    const float* dsaob = (const float*)d_in[22];
    const float* dcaqw = (const float*)d_in[23];
    const float* dcaqb = (const float*)d_in[24];
    const float* dcaow = (const float*)d_in[25];
    const float* dcaob = (const float*)d_in[26];
    const float* dln1g = (const float*)d_in[27];
    const float* dln1b = (const float*)d_in[28];
    const float* dln2g = (const float*)d_in[29];
    const float* dln2b = (const float*)d_in[30];
    const float* dln3g = (const float*)d_in[31];
    const float* dln3b = (const float*)d_in[32];
    const float* df1w  = (const float*)d_in[33];
    const float* df1b  = (const float*)d_in[34];
    const float* df2w  = (const float*)d_in[35];
    const float* df2b  = (const float*)d_in[36];
    float* out = (float*)d_out;

    float* ws = (float*)d_ws;
    float* pe     = ws;                       // 8192
    float* x      = pe + 8192;                // 1572864
    float* qkv    = x + 1572864;              // 4718592 (also reused as oproj output)
    float* scores = qkv + 4718592;            // 1179648
    float* attn   = scores + 1179648;         // 1572864
    float* mem    = attn + 1572864;           // 9216
    float* kmem   = mem + 9216;               // 36864
    float* vmem   = kmem + 36864;             // 36864
    float* yb     = qkv;                      // alias: Q/K/V dead after PV

    pe_k<<<16, 256, 0, stream>>>(pe);
    embed_k<<<NTOK, 256, 0, stream>>>(src, wemb, semb, pe, x);

    for (int l = 0; l < NLAY; ++l) {
        // QKV projection: (3072,512) @ (1536,512)^T
        gemm64<true><<<dim3(48, 24, 1), 256, 0, stream>>>(
            x, 512, 0, 0,
            eqkvw + (size_t)l * 786432, 512, 0, 0,
            qkv, 1536, 0, 0,
            512, eqkvb + l * 1536, 1.0f, 1);
        // scores = Q K^T / 16  : batched over (b,h)
        gemm64<true><<<dim3(3, 3, 32), 256, 0, stream>>>(
            qkv, 1536, 294912, 256,
            qkv + 512, 1536, 294912, 256,
            scores, 192, 73728, 36864,
            256, nullptr, 0.0625f, 2);
        enc_softmax<<<1536, 256, 0, stream>>>(scores);
        // attn = P @ V (NN)
        gemm64<false><<<dim3(3, 4, 32), 256, 0, stream>>>(
            scores, 192, 73728, 36864,
            qkv + 1024, 1536, 294912, 256,
            attn, 512, 98304, 256,
            192, nullptr, 1.0f, 2);
        // out-proj: (3072,512) @ (512,512)^T  -> yb (aliases qkv)
        gemm64<true><<<dim3(48, 8, 1), 256, 0, stream>>>(
            attn, 512, 0, 0,
            eow + (size_t)l * 262144, 512, 0, 0,
            yb, 512, 0, 0,
            512, eob + l * 512, 1.0f, 1);
        res_ln<<<NTOK, 256, 0, stream>>>(x, yb, eln1g + l * 512, eln1b + l * 512);
        enc_ffn_ln<<<NTOK, 256, 0, stream>>>(x, ef1w + l * 2048, ef1b + l * 4,
                                             ef2w + l * 2048, ef2b + l * 512,
                                             eln2g + l * 512, eln2b + l * 512);
    }

    eout_k<<<NTOK, 256, 0, stream>>>(x, nfg, nfb, eoutw, eoutb, src, mem, out);
    crosskv_k<<<48, 256, 0, stream>>>(mem, dcaqw, dcaqb, kmem, vmem);
    decoder_ar<<<BATCH, 64, 0, stream>>>(kmem, vmem,
        dsaqw, dsaqb, dsaow, dsaob, dcaqw, dcaqb, dcaow, dcaob,
        dln1g, dln1b, dln2g, dln2b, dln3g, dln3b,
        df1w, df1b, df2w, df2b, out);
}

// Round 8
// 1820.925 us; speedup vs baseline: 1.0048x; 1.0048x over previous
//
#include <hip/hip_runtime.h>
#include <math.h>
#include <stdint.h>

// ---------------- constants ----------------
#define BATCH 16
#define SLEN  192
#define DMODEL 512
#define UIN   258
#define NTOK  (BATCH*SLEN)      // 3072
#define NLAY  4

// ---------------- positional encoding table (16 x 512) ----------------
__global__ void pe_k(float* __restrict__ pe) {
    int b = blockIdx.x;          // 0..15
    int i = threadIdx.x;         // 0..255
    float div = expf((float)(2 * i) * (-9.210340371976184f / 512.0f));
    float a = (float)b * div;
    pe[b * 512 + 2 * i]     = sinf(a);
    pe[b * 512 + 2 * i + 1] = cosf(a);
}

// ---------------- embed + PE ----------------
__global__ __launch_bounds__(256) void embed_k(
    const float* __restrict__ src, const float* __restrict__ wemb,
    const float* __restrict__ semb, const float* __restrict__ pe,
    float* __restrict__ x)
{
    int n = blockIdx.x;                 // token
    int b = n / SLEN;
    int t = threadIdx.x;
    int wi = (int)src[(size_t)n * UIN + 256];
    int si = (int)src[(size_t)n * UIN + 257];
    float v0 = src[(size_t)n * UIN + t];
    x[(size_t)n * 512 + t] = v0 + pe[b * 512 + t];
    int d = t + 256;
    float v1 = (d < 384) ? wemb[(size_t)wi * 128 + (d - 256)]
                         : semb[(size_t)si * 128 + (d - 384)];
    x[(size_t)n * 512 + d] = v1 + pe[b * 512 + d];
}

// ---------------- generic 64x64 tiled GEMM: C = alpha*A@op(B) + bias ----------------
template <bool BT>
__global__ __launch_bounds__(256) void gemm64(
    const float* __restrict__ A, int lda, long long sAb, long long sAh,
    const float* __restrict__ B, int ldb, long long sBb, long long sBh,
    float* __restrict__ C, int ldc, long long sCb, long long sCh,
    int K, const float* __restrict__ bias, float alpha, int nh)
{
    int z = blockIdx.z;
    int zb = z / nh, zh = z - zb * nh;
    A += (size_t)zb * sAb + (size_t)zh * sAh;
    B += (size_t)zb * sBb + (size_t)zh * sBh;
    C += (size_t)zb * sCb + (size_t)zh * sCh;

    __shared__ float As[16][68];
    __shared__ float Bs[16][68];

    int t = threadIdx.x;
    int row0 = blockIdx.x * 64, col0 = blockIdx.y * 64;
    int lr = t >> 2, lk = (t & 3) << 2;
    int brow = t >> 4, bcol = (t & 15) << 2;
    int ty = (t >> 4) << 2, tx = (t & 15) << 2;

    float acc[4][4] = {};

    for (int k0 = 0; k0 < K; k0 += 16) {
        float4 a4 = *(const float4*)(A + (size_t)(row0 + lr) * lda + k0 + lk);
        As[lk][lr] = a4.x; As[lk + 1][lr] = a4.y; As[lk + 2][lr] = a4.z; As[lk + 3][lr] = a4.w;
        if (BT) {
            float4 b4 = *(const float4*)(B + (size_t)(col0 + lr) * ldb + k0 + lk);
            Bs[lk][lr] = b4.x; Bs[lk + 1][lr] = b4.y; Bs[lk + 2][lr] = b4.z; Bs[lk + 3][lr] = b4.w;
        } else {
            float4 b4 = *(const float4*)(B + (size_t)(k0 + brow) * ldb + col0 + bcol);
            *(float4*)&Bs[brow][bcol] = b4;
        }
        __syncthreads();
#pragma unroll
        for (int k = 0; k < 16; ++k) {
            const float4 av = *(const float4*)&As[k][ty];
            const float4 bv = *(const float4*)&Bs[k][tx];
            acc[0][0] += av.x * bv.x; acc[0][1] += av.x * bv.y; acc[0][2] += av.x * bv.z; acc[0][3] += av.x * bv.w;
            acc[1][0] += av.y * bv.x; acc[1][1] += av.y * bv.y; acc[1][2] += av.y * bv.z; acc[1][3] += av.y * bv.w;
            acc[2][0] += av.z * bv.x; acc[2][1] += av.z * bv.y; acc[2][2] += av.z * bv.z; acc[2][3] += av.z * bv.w;
            acc[3][0] += av.w * bv.x; acc[3][1] += av.w * bv.y; acc[3][2] += av.w * bv.z; acc[3][3] += av.w * bv.w;
        }
        __syncthreads();
    }
#pragma unroll
    for (int i2 = 0; i2 < 4; ++i2) {
        size_t crow = (size_t)(row0 + ty + i2) * ldc + col0 + tx;
#pragma unroll
        for (int j = 0; j < 4; ++j) {
            float v = alpha * acc[i2][j];
            if (bias) v += bias[col0 + tx + j];
            C[crow + j] = v;
        }
    }
}

// ---------------- encoder softmax: rows of 192, 1 wave per row ----------------
__global__ __launch_bounds__(256) void enc_softmax(float* __restrict__ scores) {
    int row = blockIdx.x * 4 + (threadIdx.x >> 6);
    int lane = threadIdx.x & 63;
    float* p = scores + (size_t)row * 192;
    float v0 = p[lane], v1 = p[lane + 64], v2 = p[lane + 128];
    float m = fmaxf(fmaxf(v0, v1), v2);
#pragma unroll
    for (int s = 1; s < 64; s <<= 1) m = fmaxf(m, __shfl_xor(m, s));
    float e0 = __expf(v0 - m), e1 = __expf(v1 - m), e2 = __expf(v2 - m);
    float sm = e0 + e1 + e2;
#pragma unroll
    for (int s = 1; s < 64; s <<= 1) sm += __shfl_xor(sm, s);
    float r = 1.0f / sm;
    p[lane] = e0 * r; p[lane + 64] = e1 * r; p[lane + 128] = e2 * r;
}

// ---------------- residual + LN (512) ----------------
__global__ __launch_bounds__(256) void res_ln(
    float* __restrict__ x, const float* __restrict__ y,
    const float* __restrict__ g, const float* __restrict__ bb)
{
    int n = blockIdx.x, t = threadIdx.x, wave = t >> 6, lane = t & 63;
    __shared__ float red[16];
    size_t base = (size_t)n * 512;
    float z0 = x[base + t] + y[base + t];
    float z1 = x[base + t + 256] + y[base + t + 256];
    float s = z0 + z1, sq = z0 * z0 + z1 * z1;
#pragma unroll
    for (int m = 1; m < 64; m <<= 1) { s += __shfl_xor(s, m); sq += __shfl_xor(sq, m); }
    if (lane == 0) { red[wave] = s; red[8 + wave] = sq; }
    __syncthreads();
    if (t == 0) {
        float S = red[0] + red[1] + red[2] + red[3];
        float Q = red[8] + red[9] + red[10] + red[11];
        float mean = S * (1.0f / 512.0f);
        float var = Q * (1.0f / 512.0f) - mean * mean;
        red[0] = mean; red[1] = 1.0f / sqrtf(var + 1e-5f);
    }
    __syncthreads();
    float mean = red[0], rs = red[1];
    x[base + t]       = (z0 - mean) * rs * g[t] + bb[t];
    x[base + t + 256] = (z1 - mean) * rs * g[t + 256] + bb[t + 256];
}

// ---------------- fused FFN (512->4 relu ->512) + residual + LN ----------------
__global__ __launch_bounds__(256) void enc_ffn_ln(
    float* __restrict__ x,
    const float* __restrict__ w1, const float* __restrict__ b1,
    const float* __restrict__ w2, const float* __restrict__ b2,
    const float* __restrict__ g, const float* __restrict__ bb)
{
    int n = blockIdx.x, t = threadIdx.x, wave = t >> 6, lane = t & 63;
    __shared__ float xs[512];
    __shared__ float hs[4];
    __shared__ float red[16];
    size_t base = (size_t)n * 512;
    float x0 = x[base + t], x1 = x[base + t + 256];
    xs[t] = x0; xs[t + 256] = x1;
    __syncthreads();
    float p = 0.0f;
    for (int c = lane; c < 512; c += 64) p += xs[c] * w1[wave * 512 + c];
#pragma unroll
    for (int m = 1; m < 64; m <<= 1) p += __shfl_xor(p, m);
    if (lane == 0) hs[wave] = fmaxf(p + b1[wave], 0.0f);
    __syncthreads();
    float h0 = hs[0], h1 = hs[1], h2 = hs[2], h3 = hs[3];
    int t2 = t + 256;
    float z0 = x0 + b2[t]  + h0 * w2[t * 4]  + h1 * w2[t * 4 + 1]  + h2 * w2[t * 4 + 2]  + h3 * w2[t * 4 + 3];
    float z1 = x1 + b2[t2] + h0 * w2[t2 * 4] + h1 * w2[t2 * 4 + 1] + h2 * w2[t2 * 4 + 2] + h3 * w2[t2 * 4 + 3];
    float s = z0 + z1, sq = z0 * z0 + z1 * z1;
#pragma unroll
    for (int m = 1; m < 64; m <<= 1) { s += __shfl_xor(s, m); sq += __shfl_xor(sq, m); }
    if (lane == 0) { red[wave] = s; red[8 + wave] = sq; }
    __syncthreads();
    if (t == 0) {
        float S = red[0] + red[1] + red[2] + red[3];
        float Q = red[8] + red[9] + red[10] + red[11];
        float mean = S * (1.0f / 512.0f);
        float var = Q * (1.0f / 512.0f) - mean * mean;
        red[0] = mean; red[1] = 1.0f / sqrtf(var + 1e-5f);
    }
    __syncthreads();
    float mean = red[0], rs = red[1];
    x[base + t]  = (z0 - mean) * rs * g[t]  + bb[t];
    x[base + t2] = (z1 - mean) * rs * g[t2] + bb[t2];
}

// ---------------- final LN + eout projection (512->3) + copy index cols ----------------
__global__ __launch_bounds__(256) void eout_k(
    const float* __restrict__ x,
    const float* __restrict__ g, const float* __restrict__ bb,
    const float* __restrict__ ew, const float* __restrict__ eb,
    const float* __restrict__ src, float* __restrict__ mem, float* __restrict__ out)
{
    int n = blockIdx.x, t = threadIdx.x, wave = t >> 6, lane = t & 63;
    __shared__ float xs[512];
    __shared__ float red[16];
    size_t base = (size_t)n * 512;
    float z0 = x[base + t], z1 = x[base + t + 256];
    float s = z0 + z1, sq = z0 * z0 + z1 * z1;
#pragma unroll
    for (int m = 1; m < 64; m <<= 1) { s += __shfl_xor(s, m); sq += __shfl_xor(sq, m); }
    if (lane == 0) { red[wave] = s; red[8 + wave] = sq; }
    __syncthreads();
    if (t == 0) {
        float S = red[0] + red[1] + red[2] + red[3];
        float Q = red[8] + red[9] + red[10] + red[11];
        float mean = S * (1.0f / 512.0f);
        float var = Q * (1.0f / 512.0f) - mean * mean;
        red[0] = mean; red[1] = 1.0f / sqrtf(var + 1e-5f);
    }
    __syncthreads();
    float mean = red[0], rs = red[1];
    xs[t]       = (z0 - mean) * rs * g[t] + bb[t];
    xs[t + 256] = (z1 - mean) * rs * g[t + 256] + bb[t + 256];
    __syncthreads();
    if (wave < 3) {
        float p = 0.0f;
        for (int c = lane; c < 512; c += 64) p += xs[c] * ew[wave * 512 + c];
#pragma unroll
        for (int m = 1; m < 64; m <<= 1) p += __shfl_xor(p, m);
        if (lane == 0) mem[(size_t)n * 3 + wave] = p + eb[wave];
    }
    if (t == 0) {
        out[(size_t)n * 5 + 3] = src[(size_t)n * UIN + 256];
        out[(size_t)n * 5 + 4] = src[(size_t)n * UIN + 257];
    }
}

// ---------------- precompute cross-attention K/V of memory per layer ----------------
// layout: kmem[b][l][s][3]
__global__ __launch_bounds__(256) void crosskv_k(
    const float* __restrict__ mem, const float* __restrict__ w, const float* __restrict__ bias,
    float* __restrict__ kmem, float* __restrict__ vmem)
{
    int idx = blockIdx.x * 256 + threadIdx.x;   // < 16*4*192
    int s = idx % SLEN;
    int l = (idx / SLEN) & 3;
    int b = idx / (SLEN * 4);
    const float* m = mem + ((size_t)b * SLEN + s) * 3;
    float m0 = m[0], m1 = m[1], m2 = m[2];
    const float* wl = w + l * 27;
    const float* bl = bias + l * 9;
    float* kp = kmem + (size_t)idx * 3;
    float* vp = vmem + (size_t)idx * 3;
#pragma unroll
    for (int r = 0; r < 3; ++r) {
        kp[r] = wl[(3 + r) * 3] * m0 + wl[(3 + r) * 3 + 1] * m1 + wl[(3 + r) * 3 + 2] * m2 + bl[3 + r];
        vp[r] = wl[(6 + r) * 3] * m0 + wl[(6 + r) * 3 + 1] * m1 + wl[(6 + r) * 3 + 2] * m2 + bl[6 + r];
    }
}

// ---------------- DPP wave-64 sum reduce (VALU latency, no LDS pipe) ----------------
template <int CTRL>
__device__ __forceinline__ float dpp_add(float x) {
    int s = __builtin_amdgcn_update_dpp(0, __float_as_int(x), CTRL, 0xf, 0xf, true);
    return x + __int_as_float(s);
}
__device__ __forceinline__ float wave_sum64(float x) {
    x = dpp_add<0x111>(x);   // row_shr:1
    x = dpp_add<0x112>(x);   // row_shr:2
    x = dpp_add<0x114>(x);   // row_shr:4
    x = dpp_add<0x118>(x);   // row_shr:8
    x = dpp_add<0x142>(x);   // row_bcast:15
    x = dpp_add<0x143>(x);   // row_bcast:31
    return __int_as_float(__builtin_amdgcn_readlane(__float_as_int(x), 63));
}

// ======== decoder register-file state: NAMED SCALARS ONLY (no arrays!) =======
// R6 evidence: array-based K/V state stayed at VGPR_Count=92 (scratch), PIN
// was a no-op. Named scalars + manual layer unroll make scratch impossible.
// Index convention: name##(s*3+r), slot s = position s*64+lane.
#define D9(n) float n##0=0.f,n##1=0.f,n##2=0.f,n##3=0.f,n##4=0.f,n##5=0.f,n##6=0.f,n##7=0.f,n##8=0.f

#define LOADM(L) do { \
    size_t base_ = (((size_t)(b * 4 + L)) * SLEN + lane) * 3; \
    Km##L##_0 = kmem[base_];       Km##L##_1 = kmem[base_ + 1];   Km##L##_2 = kmem[base_ + 2]; \
    Km##L##_3 = kmem[base_ + 192]; Km##L##_4 = kmem[base_ + 193]; Km##L##_5 = kmem[base_ + 194]; \
    Km##L##_6 = kmem[base_ + 384]; Km##L##_7 = kmem[base_ + 385]; Km##L##_8 = kmem[base_ + 386]; \
    Vm##L##_0 = vmem[base_];       Vm##L##_1 = vmem[base_ + 1];   Vm##L##_2 = vmem[base_ + 2]; \
    Vm##L##_3 = vmem[base_ + 192]; Vm##L##_4 = vmem[base_ + 193]; Vm##L##_5 = vmem[base_ + 194]; \
    Vm##L##_6 = vmem[base_ + 384]; Vm##L##_7 = vmem[base_ + 385]; Vm##L##_8 = vmem[base_ + 386]; \
} while (0)

#define LN3S(Gp, Bp) { \
    const float* G_ = (Gp); const float* B_ = (Bp); \
    float mn_ = (y0 + y1 + y2) * (1.0f / 3.0f); \
    float d0_ = y0 - mn_, d1_ = y1 - mn_, d2_ = y2 - mn_; \
    float rs_ = 1.0f / sqrtf((d0_ * d0_ + d1_ * d1_ + d2_ * d2_) * (1.0f / 3.0f) + 1e-5f); \
    y0 = d0_ * rs_ * G_[0] + B_[0]; y1 = d1_ * rs_ * G_[1] + B_[1]; y2 = d2_ * rs_ * G_[2] + B_[2]; }

#define LAYER(L) { \
    const float* W  = sa_qkv_w + L * 27; const float* Bw = sa_qkv_b + L * 9; \
    float q0 = (W[0] * y0 + W[1] * y1 + W[2] * y2 + Bw[0]) * isc; \
    float q1 = (W[3] * y0 + W[4] * y1 + W[5] * y2 + Bw[1]) * isc; \
    float q2 = (W[6] * y0 + W[7] * y1 + W[8] * y2 + Bw[2]) * isc; \
    float k0 = W[9]  * y0 + W[10] * y1 + W[11] * y2 + Bw[3]; \
    float k1 = W[12] * y0 + W[13] * y1 + W[14] * y2 + Bw[4]; \
    float k2 = W[15] * y0 + W[16] * y1 + W[17] * y2 + Bw[5]; \
    float v0 = W[18] * y0 + W[19] * y1 + W[20] * y2 + Bw[6]; \
    float v1 = W[21] * y0 + W[22] * y1 + W[23] * y2 + Bw[7]; \
    float v2 = W[24] * y0 + W[25] * y1 + W[26] * y2 + Bw[8]; \
    if (slot == 0) { \
        Kc##L##_0 = mine ? k0 : Kc##L##_0; Kc##L##_1 = mine ? k1 : Kc##L##_1; Kc##L##_2 = mine ? k2 : Kc##L##_2; \
        Vc##L##_0 = mine ? v0 : Vc##L##_0; Vc##L##_1 = mine ? v1 : Vc##L##_1; Vc##L##_2 = mine ? v2 : Vc##L##_2; \
    } else if (slot == 1) { \
        Kc##L##_3 = mine ? k0 : Kc##L##_3; Kc##L##_4 = mine ? k1 : Kc##L##_4; Kc##L##_5 = mine ? k2 : Kc##L##_5; \
        Vc##L##_3 = mine ? v0 : Vc##L##_3; Vc##L##_4 = mine ? v1 : Vc##L##_4; Vc##L##_5 = mine ? v2 : Vc##L##_5; \
    } else { \
        Kc##L##_6 = mine ? k0 : Kc##L##_6; Kc##L##_7 = mine ? k1 : Kc##L##_7; Kc##L##_8 = mine ? k2 : Kc##L##_8; \
        Vc##L##_6 = mine ? v0 : Vc##L##_6; Vc##L##_7 = mine ? v1 : Vc##L##_7; Vc##L##_8 = mine ? v2 : Vc##L##_8; \
    } \
    float den, a0, a1, a2; \
    { \
        float sc0 = q0 * Kc##L##_0 + q1 * Kc##L##_1 + q2 * Kc##L##_2; \
        float sc1 = q0 * Kc##L##_3 + q1 * Kc##L##_4 + q2 * Kc##L##_5; \
        float sc2 = q0 * Kc##L##_6 + q1 * Kc##L##_7 + q2 * Kc##L##_8; \
        float e0 = (lane       <= i) ? __expf(sc0) : 0.0f; \
        float e1 = (lane + 64  <= i) ? __expf(sc1) : 0.0f; \
        float e2 = (lane + 128 <= i) ? __expf(sc2) : 0.0f; \
        den = e0 + e1 + e2; \
        a0 = e0 * Vc##L##_0 + e1 * Vc##L##_3 + e2 * Vc##L##_6; \
        a1 = e0 * Vc##L##_1 + e1 * Vc##L##_4 + e2 * Vc##L##_7; \
        a2 = e0 * Vc##L##_2 + e1 * Vc##L##_5 + e2 * Vc##L##_8; \
    } \
    den = wave_sum64(den); a0 = wave_sum64(a0); a1 = wave_sum64(a1); a2 = wave_sum64(a2); \
    { \
        float ri = 1.0f / den; float o0 = a0 * ri, o1 = a1 * ri, o2 = a2 * ri; \
        const float* Ow = sa_o_w + L * 9; const float* Ob = sa_o_b + L * 3; \
        y0 += Ow[0] * o0 + Ow[1] * o1 + Ow[2] * o2 + Ob[0]; \
        y1 += Ow[3] * o0 + Ow[4] * o1 + Ow[5] * o2 + Ob[1]; \
        y2 += Ow[6] * o0 + Ow[7] * o1 + Ow[8] * o2 + Ob[2]; \
    } \
    LN3S(ln1g + L * 3, ln1b + L * 3); \
    { \
        const float* Cw = ca_qkv_w + L * 27; const float* Cb = ca_qkv_b + L * 9; \
        float c0 = (Cw[0] * y0 + Cw[1] * y1 + Cw[2] * y2 + Cb[0]) * isc; \
        float c1 = (Cw[3] * y0 + Cw[4] * y1 + Cw[5] * y2 + Cb[1]) * isc; \
        float c2 = (Cw[6] * y0 + Cw[7] * y1 + Cw[8] * y2 + Cb[2]) * isc; \
        float sc0 = c0 * Km##L##_0 + c1 * Km##L##_1 + c2 * Km##L##_2; \
        float sc1 = c0 * Km##L##_3 + c1 * Km##L##_4 + c2 * Km##L##_5; \
        float sc2 = c0 * Km##L##_6 + c1 * Km##L##_7 + c2 * Km##L##_8; \
        float e0 = __expf(sc0), e1 = __expf(sc1), e2 = __expf(sc2); \
        den = e0 + e1 + e2; \
        a0 = e0 * Vm##L##_0 + e1 * Vm##L##_3 + e2 * Vm##L##_6; \
        a1 = e0 * Vm##L##_1 + e1 * Vm##L##_4 + e2 * Vm##L##_7; \
        a2 = e0 * Vm##L##_2 + e1 * Vm##L##_5 + e2 * Vm##L##_8; \
    } \
    den = wave_sum64(den); a0 = wave_sum64(a0); a1 = wave_sum64(a1); a2 = wave_sum64(a2); \
    { \
        float ri = 1.0f / den; float o0 = a0 * ri, o1 = a1 * ri, o2 = a2 * ri; \
        const float* Co = ca_o_w + L * 9; const float* Cob = ca_o_b + L * 3; \
        y0 += Co[0] * o0 + Co[1] * o1 + Co[2] * o2 + Cob[0]; \
        y1 += Co[3] * o0 + Co[4] * o1 + Co[5] * o2 + Cob[1]; \
        y2 += Co[6] * o0 + Co[7] * o1 + Co[8] * o2 + Cob[2]; \
    } \
    LN3S(ln2g + L * 3, ln2b + L * 3); \
    { \
        const float* F1 = f1w + L * 12; const float* FB1 = f1b + L * 4; \
        const float* F2 = f2w + L * 12; const float* FB2 = f2b + L * 3; \
        float h0 = fmaxf(F1[0] * y0 + F1[1]  * y1 + F1[2]  * y2 + FB1[0], 0.f); \
        float h1 = fmaxf(F1[3] * y0 + F1[4]  * y1 + F1[5]  * y2 + FB1[1], 0.f); \
        float h2 = fmaxf(F1[6] * y0 + F1[7]  * y1 + F1[8]  * y2 + FB1[2], 0.f); \
        float h3 = fmaxf(F1[9] * y0 + F1[10] * y1 + F1[11] * y2 + FB1[3], 0.f); \
        y0 += F2[0] * h0 + F2[1] * h1 + F2[2]  * h2 + F2[3]  * h3 + FB2[0]; \
        y1 += F2[4] * h0 + F2[5] * h1 + F2[6]  * h2 + F2[7]  * h3 + FB2[1]; \
        y2 += F2[8] * h0 + F2[9] * h1 + F2[10] * h2 + F2[11] * h3 + FB2[2]; \
    } \
    LN3S(ln3g + L * 3, ln3b + L * 3); \
}

// ---------------- autoregressive decoder: 1 block (1 wave) per batch ----------------
__global__ __launch_bounds__(64, 1) void decoder_ar(
    const float* __restrict__ kmem, const float* __restrict__ vmem,
    const float* __restrict__ sa_qkv_w, const float* __restrict__ sa_qkv_b,
    const float* __restrict__ sa_o_w, const float* __restrict__ sa_o_b,
    const float* __restrict__ ca_qkv_w, const float* __restrict__ ca_qkv_b,
    const float* __restrict__ ca_o_w, const float* __restrict__ ca_o_b,
    const float* __restrict__ ln1g, const float* __restrict__ ln1b,
    const float* __restrict__ ln2g, const float* __restrict__ ln2b,
    const float* __restrict__ ln3g, const float* __restrict__ ln3b,
    const float* __restrict__ f1w, const float* __restrict__ f1b,
    const float* __restrict__ f2w, const float* __restrict__ f2b,
    float* __restrict__ out)
{
    int b = blockIdx.x, lane = threadIdx.x;
    const float isc = 0.57735026918962576f;   // 1/sqrt(3)

    D9(Km0_); D9(Km1_); D9(Km2_); D9(Km3_);
    D9(Vm0_); D9(Vm1_); D9(Vm2_); D9(Vm3_);
    D9(Kc0_); D9(Kc1_); D9(Kc2_); D9(Kc3_);
    D9(Vc0_); D9(Vc1_); D9(Vc2_); D9(Vc3_);

    LOADM(0); LOADM(1); LOADM(2); LOADM(3);

    if (lane < 3) out[(size_t)(b * SLEN) * 5 + lane] = 0.0f;   // tgt[b,0,:] = 0

    float y0 = 0.0f, y1 = 0.0f, y2 = 0.0f;

    for (int i = 0; i < SLEN - 1; ++i) {
        int slot = i >> 6;          // wave-uniform
        bool mine = (lane == (i & 63));
        LAYER(0)
        LAYER(1)
        LAYER(2)
        LAYER(3)
        if (lane == 0) {
            size_t o = (size_t)(b * SLEN + i + 1) * 5;
            out[o] = y0; out[o + 1] = y1; out[o + 2] = y2;
        }
    }
}

// ---------------- host launcher ----------------
extern "C" void kernel_launch(void* const* d_in, const int* in_sizes, int n_in,
                              void* d_out, int out_size, void* d_ws, size_t ws_size,
                              hipStream_t stream)
{
    const float* src   = (const float*)d_in[0];
    const float* wemb  = (const float*)d_in[1];
    const float* semb  = (const float*)d_in[2];
    const float* eqkvw = (const float*)d_in[3];
    const float* eqkvb = (const float*)d_in[4];
    const float* eow   = (const float*)d_in[5];
    const float* eob   = (const float*)d_in[6];
    const float* eln1g = (const float*)d_in[7];
    const float* eln1b = (const float*)d_in[8];
    const float* ef1w  = (const float*)d_in[9];
    const float* ef1b  = (const float*)d_in[10];
    const float* ef2w  = (const float*)d_in[11];
    const float* ef2b  = (const float*)d_in[12];
    const float* eln2g = (const float*)d_in[13];
    const float* eln2b = (const float*)d_in[14];
    const float* nfg   = (const float*)d_in[15];
    const float* nfb   = (const float*)d_in[16];
    const float* eoutw = (const float*)d_in[17];
    const float* eoutb = (const float*)d_in[18];
    const float* dsaqw = (const float*)d_in[19];
    const float* dsaqb = (const float*)d_in[20];
    const float* dsaow = (const float*)d_in[21];
    const float* dsaob = (const float*)d_in[22];
    const float* dcaqw = (const float*)d_in[23];
    const float* dcaqb = (const float*)d_in[24];
    const float* dcaow = (const float*)d_in[25];
    const float* dcaob = (const float*)d_in[26];
    const float* dln1g = (const float*)d_in[27];
    const float* dln1b = (const float*)d_in[28];
    const float* dln2g = (const float*)d_in[29];
    const float* dln2b = (const float*)d_in[30];
    const float* dln3g = (const float*)d_in[31];
    const float* dln3b = (const float*)d_in[32];
    const float* df1w  = (const float*)d_in[33];
    const float* df1b  = (const float*)d_in[34];
    const float* df2w  = (const float*)d_in[35];
    const float* df2b  = (const float*)d_in[36];
    float* out = (float*)d_out;

    float* ws = (float*)d_ws;
    float* pe     = ws;                       // 8192
    float* x      = pe + 8192;                // 1572864
    float* qkv    = x + 1572864;              // 4718592 (also reused as oproj output)
    float* scores = qkv + 4718592;            // 1179648
    float* attn   = scores + 1179648;         // 1572864
    float* mem    = attn + 1572864;           // 9216
    float* kmem   = mem + 9216;               // 36864
    float* vmem   = kmem + 36864;             // 36864
    float* yb     = qkv;                      // alias: Q/K/V dead after PV

    pe_k<<<16, 256, 0, stream>>>(pe);
    embed_k<<<NTOK, 256, 0, stream>>>(src, wemb, semb, pe, x);

    for (int l = 0; l < NLAY; ++l) {
        // QKV projection: (3072,512) @ (1536,512)^T
        gemm64<true><<<dim3(48, 24, 1), 256, 0, stream>>>(
            x, 512, 0, 0,
            eqkvw + (size_t)l * 786432, 512, 0, 0,
            qkv, 1536, 0, 0,
            512, eqkvb + l * 1536, 1.0f, 1);
        // scores = Q K^T / 16  : batched over (b,h)
        gemm64<true><<<dim3(3, 3, 32), 256, 0, stream>>>(
            qkv, 1536, 294912, 256,
            qkv + 512, 1536, 294912, 256,
            scores, 192, 73728, 36864,
            256, nullptr, 0.0625f, 2);
        enc_softmax<<<1536, 256, 0, stream>>>(scores);
        // attn = P @ V (NN)
        gemm64<false><<<dim3(3, 4, 32), 256, 0, stream>>>(
            scores, 192, 73728, 36864,
            qkv + 1024, 1536, 294912, 256,
            attn, 512, 98304, 256,
            192, nullptr, 1.0f, 2);
        // out-proj: (3072,512) @ (512,512)^T  -> yb (aliases qkv)
        gemm64<true><<<dim3(48, 8, 1), 256, 0, stream>>>(
            attn, 512, 0, 0,
            eow + (size_t)l * 262144, 512, 0, 0,
            yb, 512, 0, 0,
            512, eob + l * 512, 1.0f, 1);
        res_ln<<<NTOK, 256, 0, stream>>>(x, yb, eln1g + l * 512, eln1b + l * 512);
        enc_ffn_ln<<<NTOK, 256, 0, stream>>>(x, ef1w + l * 2048, ef1b + l * 4,
                                             ef2w + l * 2048, ef2b + l * 512,
                                             eln2g + l * 512, eln2b + l * 512);
    }

    eout_k<<<NTOK, 256, 0, stream>>>(x, nfg, nfb, eoutw, eoutb, src, mem, out);
    crosskv_k<<<48, 256, 0, stream>>>(mem, dcaqw, dcaqb, kmem, vmem);
    decoder_ar<<<BATCH, 64, 0, stream>>>(kmem, vmem,
        dsaqw, dsaqb, dsaow, dsaob, dcaqw, dcaqb, dcaow, dcaob,
        dln1g, dln1b, dln2g, dln2b, dln3g, dln3b,
        df1w, df1b, df2w, df2b, out);
}

// Round 10
// 1765.159 us; speedup vs baseline: 1.0366x; 1.0316x over previous
//
#include <hip/hip_runtime.h>
#include <math.h>
#include <stdint.h>

// ---------------- constants ----------------
#define BATCH 16
#define SLEN  192
#define DMODEL 512
#define UIN   258
#define NTOK  (BATCH*SLEN)      // 3072
#define NLAY  4

// ---------------- positional encoding table (16 x 512) ----------------
__global__ void pe_k(float* __restrict__ pe) {
    int b = blockIdx.x;          // 0..15
    int i = threadIdx.x;         // 0..255
    float div = expf((float)(2 * i) * (-9.210340371976184f / 512.0f));
    float a = (float)b * div;
    pe[b * 512 + 2 * i]     = sinf(a);
    pe[b * 512 + 2 * i + 1] = cosf(a);
}

// ---------------- embed + PE ----------------
__global__ __launch_bounds__(256) void embed_k(
    const float* __restrict__ src, const float* __restrict__ wemb,
    const float* __restrict__ semb, const float* __restrict__ pe,
    float* __restrict__ x)
{
    int n = blockIdx.x;                 // token
    int b = n / SLEN;
    int t = threadIdx.x;
    int wi = (int)src[(size_t)n * UIN + 256];
    int si = (int)src[(size_t)n * UIN + 257];
    float v0 = src[(size_t)n * UIN + t];
    x[(size_t)n * 512 + t] = v0 + pe[b * 512 + t];
    int d = t + 256;
    float v1 = (d < 384) ? wemb[(size_t)wi * 128 + (d - 256)]
                         : semb[(size_t)si * 128 + (d - 384)];
    x[(size_t)n * 512 + d] = v1 + pe[b * 512 + d];
}

// ---------------- generic 64x64 tiled GEMM: C = alpha*A@op(B) + bias ----------------
template <bool BT>
__global__ __launch_bounds__(256) void gemm64(
    const float* __restrict__ A, int lda, long long sAb, long long sAh,
    const float* __restrict__ B, int ldb, long long sBb, long long sBh,
    float* __restrict__ C, int ldc, long long sCb, long long sCh,
    int K, const float* __restrict__ bias, float alpha, int nh)
{
    int z = blockIdx.z;
    int zb = z / nh, zh = z - zb * nh;
    A += (size_t)zb * sAb + (size_t)zh * sAh;
    B += (size_t)zb * sBb + (size_t)zh * sBh;
    C += (size_t)zb * sCb + (size_t)zh * sCh;

    __shared__ float As[16][68];
    __shared__ float Bs[16][68];

    int t = threadIdx.x;
    int row0 = blockIdx.x * 64, col0 = blockIdx.y * 64;
    int lr = t >> 2, lk = (t & 3) << 2;
    int brow = t >> 4, bcol = (t & 15) << 2;
    int ty = (t >> 4) << 2, tx = (t & 15) << 2;

    float acc[4][4] = {};

    for (int k0 = 0; k0 < K; k0 += 16) {
        float4 a4 = *(const float4*)(A + (size_t)(row0 + lr) * lda + k0 + lk);
        As[lk][lr] = a4.x; As[lk + 1][lr] = a4.y; As[lk + 2][lr] = a4.z; As[lk + 3][lr] = a4.w;
        if (BT) {
            float4 b4 = *(const float4*)(B + (size_t)(col0 + lr) * ldb + k0 + lk);
            Bs[lk][lr] = b4.x; Bs[lk + 1][lr] = b4.y; Bs[lk + 2][lr] = b4.z; Bs[lk + 3][lr] = b4.w;
        } else {
            float4 b4 = *(const float4*)(B + (size_t)(k0 + brow) * ldb + col0 + bcol);
            *(float4*)&Bs[brow][bcol] = b4;
        }
        __syncthreads();
#pragma unroll
        for (int k = 0; k < 16; ++k) {
            const float4 av = *(const float4*)&As[k][ty];
            const float4 bv = *(const float4*)&Bs[k][tx];
            acc[0][0] += av.x * bv.x; acc[0][1] += av.x * bv.y; acc[0][2] += av.x * bv.z; acc[0][3] += av.x * bv.w;
            acc[1][0] += av.y * bv.x; acc[1][1] += av.y * bv.y; acc[1][2] += av.y * bv.z; acc[1][3] += av.y * bv.w;
            acc[2][0] += av.z * bv.x; acc[2][1] += av.z * bv.y; acc[2][2] += av.z * bv.z; acc[2][3] += av.z * bv.w;
            acc[3][0] += av.w * bv.x; acc[3][1] += av.w * bv.y; acc[3][2] += av.w * bv.z; acc[3][3] += av.w * bv.w;
        }
        __syncthreads();
    }
#pragma unroll
    for (int i2 = 0; i2 < 4; ++i2) {
        size_t crow = (size_t)(row0 + ty + i2) * ldc + col0 + tx;
#pragma unroll
        for (int j = 0; j < 4; ++j) {
            float v = alpha * acc[i2][j];
            if (bias) v += bias[col0 + tx + j];
            C[crow + j] = v;
        }
    }
}

// ---------------- encoder softmax: rows of 192, 1 wave per row ----------------
__global__ __launch_bounds__(256) void enc_softmax(float* __restrict__ scores) {
    int row = blockIdx.x * 4 + (threadIdx.x >> 6);
    int lane = threadIdx.x & 63;
    float* p = scores + (size_t)row * 192;
    float v0 = p[lane], v1 = p[lane + 64], v2 = p[lane + 128];
    float m = fmaxf(fmaxf(v0, v1), v2);
#pragma unroll
    for (int s = 1; s < 64; s <<= 1) m = fmaxf(m, __shfl_xor(m, s));
    float e0 = __expf(v0 - m), e1 = __expf(v1 - m), e2 = __expf(v2 - m);
    float sm = e0 + e1 + e2;
#pragma unroll
    for (int s = 1; s < 64; s <<= 1) sm += __shfl_xor(sm, s);
    float r = 1.0f / sm;
    p[lane] = e0 * r; p[lane + 64] = e1 * r; p[lane + 128] = e2 * r;
}

// ---------------- residual + LN (512) ----------------
__global__ __launch_bounds__(256) void res_ln(
    float* __restrict__ x, const float* __restrict__ y,
    const float* __restrict__ g, const float* __restrict__ bb)
{
    int n = blockIdx.x, t = threadIdx.x, wave = t >> 6, lane = t & 63;
    __shared__ float red[16];
    size_t base = (size_t)n * 512;
    float z0 = x[base + t] + y[base + t];
    float z1 = x[base + t + 256] + y[base + t + 256];
    float s = z0 + z1, sq = z0 * z0 + z1 * z1;
#pragma unroll
    for (int m = 1; m < 64; m <<= 1) { s += __shfl_xor(s, m); sq += __shfl_xor(sq, m); }
    if (lane == 0) { red[wave] = s; red[8 + wave] = sq; }
    __syncthreads();
    if (t == 0) {
        float S = red[0] + red[1] + red[2] + red[3];
        float Q = red[8] + red[9] + red[10] + red[11];
        float mean = S * (1.0f / 512.0f);
        float var = Q * (1.0f / 512.0f) - mean * mean;
        red[0] = mean; red[1] = 1.0f / sqrtf(var + 1e-5f);
    }
    __syncthreads();
    float mean = red[0], rs = red[1];
    x[base + t]       = (z0 - mean) * rs * g[t] + bb[t];
    x[base + t + 256] = (z1 - mean) * rs * g[t + 256] + bb[t + 256];
}

// ---------------- fused FFN (512->4 relu ->512) + residual + LN ----------------
__global__ __launch_bounds__(256) void enc_ffn_ln(
    float* __restrict__ x,
    const float* __restrict__ w1, const float* __restrict__ b1,
    const float* __restrict__ w2, const float* __restrict__ b2,
    const float* __restrict__ g, const float* __restrict__ bb)
{
    int n = blockIdx.x, t = threadIdx.x, wave = t >> 6, lane = t & 63;
    __shared__ float xs[512];
    __shared__ float hs[4];
    __shared__ float red[16];
    size_t base = (size_t)n * 512;
    float x0 = x[base + t], x1 = x[base + t + 256];
    xs[t] = x0; xs[t + 256] = x1;
    __syncthreads();
    float p = 0.0f;
    for (int c = lane; c < 512; c += 64) p += xs[c] * w1[wave * 512 + c];
#pragma unroll
    for (int m = 1; m < 64; m <<= 1) p += __shfl_xor(p, m);
    if (lane == 0) hs[wave] = fmaxf(p + b1[wave], 0.0f);
    __syncthreads();
    float h0 = hs[0], h1 = hs[1], h2 = hs[2], h3 = hs[3];
    int t2 = t + 256;
    float z0 = x0 + b2[t]  + h0 * w2[t * 4]  + h1 * w2[t * 4 + 1]  + h2 * w2[t * 4 + 2]  + h3 * w2[t * 4 + 3];
    float z1 = x1 + b2[t2] + h0 * w2[t2 * 4] + h1 * w2[t2 * 4 + 1] + h2 * w2[t2 * 4 + 2] + h3 * w2[t2 * 4 + 3];
    float s = z0 + z1, sq = z0 * z0 + z1 * z1;
#pragma unroll
    for (int m = 1; m < 64; m <<= 1) { s += __shfl_xor(s, m); sq += __shfl_xor(sq, m); }
    if (lane == 0) { red[wave] = s; red[8 + wave] = sq; }
    __syncthreads();
    if (t == 0) {
        float S = red[0] + red[1] + red[2] + red[3];
        float Q = red[8] + red[9] + red[10] + red[11];
        float mean = S * (1.0f / 512.0f);
        float var = Q * (1.0f / 512.0f) - mean * mean;
        red[0] = mean; red[1] = 1.0f / sqrtf(var + 1e-5f);
    }
    __syncthreads();
    float mean = red[0], rs = red[1];
    x[base + t]  = (z0 - mean) * rs * g[t]  + bb[t];
    x[base + t2] = (z1 - mean) * rs * g[t2] + bb[t2];
}

// ---------------- final LN + eout projection (512->3) + copy index cols ----------------
__global__ __launch_bounds__(256) void eout_k(
    const float* __restrict__ x,
    const float* __restrict__ g, const float* __restrict__ bb,
    const float* __restrict__ ew, const float* __restrict__ eb,
    const float* __restrict__ src, float* __restrict__ mem, float* __restrict__ out)
{
    int n = blockIdx.x, t = threadIdx.x, wave = t >> 6, lane = t & 63;
    __shared__ float xs[512];
    __shared__ float red[16];
    size_t base = (size_t)n * 512;
    float z0 = x[base + t], z1 = x[base + t + 256];
    float s = z0 + z1, sq = z0 * z0 + z1 * z1;
#pragma unroll
    for (int m = 1; m < 64; m <<= 1) { s += __shfl_xor(s, m); sq += __shfl_xor(sq, m); }
    if (lane == 0) { red[wave] = s; red[8 + wave] = sq; }
    __syncthreads();
    if (t == 0) {
        float S = red[0] + red[1] + red[2] + red[3];
        float Q = red[8] + red[9] + red[10] + red[11];
        float mean = S * (1.0f / 512.0f);
        float var = Q * (1.0f / 512.0f) - mean * mean;
        red[0] = mean; red[1] = 1.0f / sqrtf(var + 1e-5f);
    }
    __syncthreads();
    float mean = red[0], rs = red[1];
    xs[t]       = (z0 - mean) * rs * g[t] + bb[t];
    xs[t + 256] = (z1 - mean) * rs * g[t + 256] + bb[t + 256];
    __syncthreads();
    if (wave < 3) {
        float p = 0.0f;
        for (int c = lane; c < 512; c += 64) p += xs[c] * ew[wave * 512 + c];
#pragma unroll
        for (int m = 1; m < 64; m <<= 1) p += __shfl_xor(p, m);
        if (lane == 0) mem[(size_t)n * 3 + wave] = p + eb[wave];
    }
    if (t == 0) {
        out[(size_t)n * 5 + 3] = src[(size_t)n * UIN + 256];
        out[(size_t)n * 5 + 4] = src[(size_t)n * UIN + 257];
    }
}

// ---------------- precompute cross-attention K/V of memory per layer ----------------
// layout: kmem[b][l][s][3]
__global__ __launch_bounds__(256) void crosskv_k(
    const float* __restrict__ mem, const float* __restrict__ w, const float* __restrict__ bias,
    float* __restrict__ kmem, float* __restrict__ vmem)
{
    int idx = blockIdx.x * 256 + threadIdx.x;   // < 16*4*192
    int s = idx % SLEN;
    int l = (idx / SLEN) & 3;
    int b = idx / (SLEN * 4);
    const float* m = mem + ((size_t)b * SLEN + s) * 3;
    float m0 = m[0], m1 = m[1], m2 = m[2];
    const float* wl = w + l * 27;
    const float* bl = bias + l * 9;
    float* kp = kmem + (size_t)idx * 3;
    float* vp = vmem + (size_t)idx * 3;
#pragma unroll
    for (int r = 0; r < 3; ++r) {
        kp[r] = wl[(3 + r) * 3] * m0 + wl[(3 + r) * 3 + 1] * m1 + wl[(3 + r) * 3 + 2] * m2 + bl[3 + r];
        vp[r] = wl[(6 + r) * 3] * m0 + wl[(6 + r) * 3 + 1] * m1 + wl[(6 + r) * 3 + 2] * m2 + bl[6 + r];
    }
}

// ---------------- DPP wave-64 sum reduce (VALU latency, no LDS pipe) ----------------
template <int CTRL>
__device__ __forceinline__ float dpp_add(float x) {
    int s = __builtin_amdgcn_update_dpp(0, __float_as_int(x), CTRL, 0xf, 0xf, true);
    return x + __int_as_float(s);
}
__device__ __forceinline__ float wave_sum64(float x) {
    x = dpp_add<0x111>(x);   // row_shr:1
    x = dpp_add<0x112>(x);   // row_shr:2
    x = dpp_add<0x114>(x);   // row_shr:4
    x = dpp_add<0x118>(x);   // row_shr:8
    x = dpp_add<0x142>(x);   // row_bcast:15
    x = dpp_add<0x143>(x);   // row_bcast:31
    return __int_as_float(__builtin_amdgcn_readlane(__float_as_int(x), 63));
}

// Opaque identity: makes the loaded value's origin invisible to the compiler,
// so re-loading (sinking the load into the loop) is illegal and the value must
// stay register-resident. R8 evidence: named scalars alone gave VGPR=92 =
// exactly Kc/Vc(72)+y+temps -> compiler was re-loading Km/Vm from L1/L2 every
// layer on the serial chain.
#define PIN(x) asm volatile("" : "+v"(x))

// ======== decoder register-file state: NAMED SCALARS ONLY (no arrays!) =======
// Index convention: name##(s*3+r), slot s = position s*64+lane.
#define D9(n) float n##0=0.f,n##1=0.f,n##2=0.f,n##3=0.f,n##4=0.f,n##5=0.f,n##6=0.f,n##7=0.f,n##8=0.f

#define LOADM(L) do { \
    size_t base_ = (((size_t)(b * 4 + L)) * SLEN + lane) * 3; \
    Km##L##_0 = kmem[base_];       Km##L##_1 = kmem[base_ + 1];   Km##L##_2 = kmem[base_ + 2]; \
    Km##L##_3 = kmem[base_ + 192]; Km##L##_4 = kmem[base_ + 193]; Km##L##_5 = kmem[base_ + 194]; \
    Km##L##_6 = kmem[base_ + 384]; Km##L##_7 = kmem[base_ + 385]; Km##L##_8 = kmem[base_ + 386]; \
    Vm##L##_0 = vmem[base_];       Vm##L##_1 = vmem[base_ + 1];   Vm##L##_2 = vmem[base_ + 2]; \
    Vm##L##_3 = vmem[base_ + 192]; Vm##L##_4 = vmem[base_ + 193]; Vm##L##_5 = vmem[base_ + 194]; \
    Vm##L##_6 = vmem[base_ + 384]; Vm##L##_7 = vmem[base_ + 385]; Vm##L##_8 = vmem[base_ + 386]; \
} while (0)

#define PINM(L) do { \
    PIN(Km##L##_0); PIN(Km##L##_1); PIN(Km##L##_2); PIN(Km##L##_3); PIN(Km##L##_4); \
    PIN(Km##L##_5); PIN(Km##L##_6); PIN(Km##L##_7); PIN(Km##L##_8); \
    PIN(Vm##L##_0); PIN(Vm##L##_1); PIN(Vm##L##_2); PIN(Vm##L##_3); PIN(Vm##L##_4); \
    PIN(Vm##L##_5); PIN(Vm##L##_6); PIN(Vm##L##_7); PIN(Vm##L##_8); \
} while (0)

#define LN3S(Gp, Bp) { \
    const float* G_ = (Gp); const float* B_ = (Bp); \
    float mn_ = (y0 + y1 + y2) * (1.0f / 3.0f); \
    float d0_ = y0 - mn_, d1_ = y1 - mn_, d2_ = y2 - mn_; \
    float rs_ = 1.0f / sqrtf((d0_ * d0_ + d1_ * d1_ + d2_ * d2_) * (1.0f / 3.0f) + 1e-5f); \
    y0 = d0_ * rs_ * G_[0] + B_[0]; y1 = d1_ * rs_ * G_[1] + B_[1]; y2 = d2_ * rs_ * G_[2] + B_[2]; }

// Branchless layer: self-K/V store via per-slot predicated selects (cndmask),
// so each layer is ONE basic block -> scheduler can batch all weight s_loads
// at layer top instead of stalling per-use.
#define LAYER(L) { \
    const float* W  = sa_qkv_w + L * 27; const float* Bw = sa_qkv_b + L * 9; \
    float q0 = (W[0] * y0 + W[1] * y1 + W[2] * y2 + Bw[0]) * isc; \
    float q1 = (W[3] * y0 + W[4] * y1 + W[5] * y2 + Bw[1]) * isc; \
    float q2 = (W[6] * y0 + W[7] * y1 + W[8] * y2 + Bw[2]) * isc; \
    float k0 = W[9]  * y0 + W[10] * y1 + W[11] * y2 + Bw[3]; \
    float k1 = W[12] * y0 + W[13] * y1 + W[14] * y2 + Bw[4]; \
    float k2 = W[15] * y0 + W[16] * y1 + W[17] * y2 + Bw[5]; \
    float v0 = W[18] * y0 + W[19] * y1 + W[20] * y2 + Bw[6]; \
    float v1 = W[21] * y0 + W[22] * y1 + W[23] * y2 + Bw[7]; \
    float v2 = W[24] * y0 + W[25] * y1 + W[26] * y2 + Bw[8]; \
    Kc##L##_0 = m0 ? k0 : Kc##L##_0; Kc##L##_1 = m0 ? k1 : Kc##L##_1; Kc##L##_2 = m0 ? k2 : Kc##L##_2; \
    Vc##L##_0 = m0 ? v0 : Vc##L##_0; Vc##L##_1 = m0 ? v1 : Vc##L##_1; Vc##L##_2 = m0 ? v2 : Vc##L##_2; \
    Kc##L##_3 = m1 ? k0 : Kc##L##_3; Kc##L##_4 = m1 ? k1 : Kc##L##_4; Kc##L##_5 = m1 ? k2 : Kc##L##_5; \
    Vc##L##_3 = m1 ? v0 : Vc##L##_3; Vc##L##_4 = m1 ? v1 : Vc##L##_4; Vc##L##_5 = m1 ? v2 : Vc##L##_5; \
    Kc##L##_6 = m2 ? k0 : Kc##L##_6; Kc##L##_7 = m2 ? k1 : Kc##L##_7; Kc##L##_8 = m2 ? k2 : Kc##L##_8; \
    Vc##L##_6 = m2 ? v0 : Vc##L##_6; Vc##L##_7 = m2 ? v1 : Vc##L##_7; Vc##L##_8 = m2 ? v2 : Vc##L##_8; \
    float den, a0, a1, a2; \
    { \
        float sc0 = q0 * Kc##L##_0 + q1 * Kc##L##_1 + q2 * Kc##L##_2; \
        float sc1 = q0 * Kc##L##_3 + q1 * Kc##L##_4 + q2 * Kc##L##_5; \
        float sc2 = q0 * Kc##L##_6 + q1 * Kc##L##_7 + q2 * Kc##L##_8; \
        float e0 = (lane       <= i) ? __expf(sc0) : 0.0f; \
        float e1 = (lane + 64  <= i) ? __expf(sc1) : 0.0f; \
        float e2 = (lane + 128 <= i) ? __expf(sc2) : 0.0f; \
        den = e0 + e1 + e2; \
        a0 = e0 * Vc##L##_0 + e1 * Vc##L##_3 + e2 * Vc##L##_6; \
        a1 = e0 * Vc##L##_1 + e1 * Vc##L##_4 + e2 * Vc##L##_7; \
        a2 = e0 * Vc##L##_2 + e1 * Vc##L##_5 + e2 * Vc##L##_8; \
    } \
    den = wave_sum64(den); a0 = wave_sum64(a0); a1 = wave_sum64(a1); a2 = wave_sum64(a2); \
    { \
        float ri = 1.0f / den; float o0 = a0 * ri, o1 = a1 * ri, o2 = a2 * ri; \
        const float* Ow = sa_o_w + L * 9; const float* Ob = sa_o_b + L * 3; \
        y0 += Ow[0] * o0 + Ow[1] * o1 + Ow[2] * o2 + Ob[0]; \
        y1 += Ow[3] * o0 + Ow[4] * o1 + Ow[5] * o2 + Ob[1]; \
        y2 += Ow[6] * o0 + Ow[7] * o1 + Ow[8] * o2 + Ob[2]; \
    } \
    LN3S(ln1g + L * 3, ln1b + L * 3); \
    { \
        const float* Cw = ca_qkv_w + L * 27; const float* Cb = ca_qkv_b + L * 9; \
        float c0 = (Cw[0] * y0 + Cw[1] * y1 + Cw[2] * y2 + Cb[0]) * isc; \
        float c1 = (Cw[3] * y0 + Cw[4] * y1 + Cw[5] * y2 + Cb[1]) * isc; \
        float c2 = (Cw[6] * y0 + Cw[7] * y1 + Cw[8] * y2 + Cb[2]) * isc; \
        float sc0 = c0 * Km##L##_0 + c1 * Km##L##_1 + c2 * Km##L##_2; \
        float sc1 = c0 * Km##L##_3 + c1 * Km##L##_4 + c2 * Km##L##_5; \
        float sc2 = c0 * Km##L##_6 + c1 * Km##L##_7 + c2 * Km##L##_8; \
        float e0 = __expf(sc0), e1 = __expf(sc1), e2 = __expf(sc2); \
        den = e0 + e1 + e2; \
        a0 = e0 * Vm##L##_0 + e1 * Vm##L##_3 + e2 * Vm##L##_6; \
        a1 = e0 * Vm##L##_1 + e1 * Vm##L##_4 + e2 * Vm##L##_7; \
        a2 = e0 * Vm##L##_2 + e1 * Vm##L##_5 + e2 * Vm##L##_8; \
    } \
    den = wave_sum64(den); a0 = wave_sum64(a0); a1 = wave_sum64(a1); a2 = wave_sum64(a2); \
    { \
        float ri = 1.0f / den; float o0 = a0 * ri, o1 = a1 * ri, o2 = a2 * ri; \
        const float* Co = ca_o_w + L * 9; const float* Cob = ca_o_b + L * 3; \
        y0 += Co[0] * o0 + Co[1] * o1 + Co[2] * o2 + Cob[0]; \
        y1 += Co[3] * o0 + Co[4] * o1 + Co[5] * o2 + Cob[1]; \
        y2 += Co[6] * o0 + Co[7] * o1 + Co[8] * o2 + Cob[2]; \
    } \
    LN3S(ln2g + L * 3, ln2b + L * 3); \
    { \
        const float* F1 = f1w + L * 12; const float* FB1 = f1b + L * 4; \
        const float* F2 = f2w + L * 12; const float* FB2 = f2b + L * 3; \
        float h0 = fmaxf(F1[0] * y0 + F1[1]  * y1 + F1[2]  * y2 + FB1[0], 0.f); \
        float h1 = fmaxf(F1[3] * y0 + F1[4]  * y1 + F1[5]  * y2 + FB1[1], 0.f); \
        float h2 = fmaxf(F1[6] * y0 + F1[7]  * y1 + F1[8]  * y2 + FB1[2], 0.f); \
        float h3 = fmaxf(F1[9] * y0 + F1[10] * y1 + F1[11] * y2 + FB1[3], 0.f); \
        y0 += F2[0] * h0 + F2[1] * h1 + F2[2]  * h2 + F2[3]  * h3 + FB2[0]; \
        y1 += F2[4] * h0 + F2[5] * h1 + F2[6]  * h2 + F2[7]  * h3 + FB2[1]; \
        y2 += F2[8] * h0 + F2[9] * h1 + F2[10] * h2 + F2[11] * h3 + FB2[2]; \
    } \
    LN3S(ln3g + L * 3, ln3b + L * 3); \
}

// ---------------- autoregressive decoder: 1 block (1 wave) per batch ----------------
__global__ __launch_bounds__(64, 1) void decoder_ar(
    const float* __restrict__ kmem, const float* __restrict__ vmem,
    const float* __restrict__ sa_qkv_w, const float* __restrict__ sa_qkv_b,
    const float* __restrict__ sa_o_w, const float* __restrict__ sa_o_b,
    const float* __restrict__ ca_qkv_w, const float* __restrict__ ca_qkv_b,
    const float* __restrict__ ca_o_w, const float* __restrict__ ca_o_b,
    const float* __restrict__ ln1g, const float* __restrict__ ln1b,
    const float* __restrict__ ln2g, const float* __restrict__ ln2b,
    const float* __restrict__ ln3g, const float* __restrict__ ln3b,
    const float* __restrict__ f1w, const float* __restrict__ f1b,
    const float* __restrict__ f2w, const float* __restrict__ f2b,
    float* __restrict__ out)
{
    int b = blockIdx.x, lane = threadIdx.x;
    const float isc = 0.57735026918962576f;   // 1/sqrt(3)

    D9(Km0_); D9(Km1_); D9(Km2_); D9(Km3_);
    D9(Vm0_); D9(Vm1_); D9(Vm2_); D9(Vm3_);
    D9(Kc0_); D9(Kc1_); D9(Kc2_); D9(Kc3_);
    D9(Vc0_); D9(Vc1_); D9(Vc2_); D9(Vc3_);

    LOADM(0); LOADM(1); LOADM(2); LOADM(3);
    PINM(0); PINM(1); PINM(2); PINM(3);

    if (lane < 3) out[(size_t)(b * SLEN) * 5 + lane] = 0.0f;   // tgt[b,0,:] = 0

    float y0 = 0.0f, y1 = 0.0f, y2 = 0.0f;

    for (int i = 0; i < SLEN - 1; ++i) {
        bool m0 = (i == lane);
        bool m1 = (i == lane + 64);
        bool m2 = (i == lane + 128);
        LAYER(0)
        LAYER(1)
        LAYER(2)
        LAYER(3)
        if (lane == 0) {
            size_t o = (size_t)(b * SLEN + i + 1) * 5;
            out[o] = y0; out[o + 1] = y1; out[o + 2] = y2;
        }
    }
}

// ---------------- host launcher ----------------
extern "C" void kernel_launch(void* const* d_in, const int* in_sizes, int n_in,
                              void* d_out, int out_size, void* d_ws, size_t ws_size,
                              hipStream_t stream)
{
    const float* src   = (const float*)d_in[0];
    const float* wemb  = (const float*)d_in[1];
    const float* semb  = (const float*)d_in[2];
    const float* eqkvw = (const float*)d_in[3];
    const float* eqkvb = (const float*)d_in[4];
    const float* eow   = (const float*)d_in[5];
    const float* eob   = (const float*)d_in[6];
    const float* eln1g = (const float*)d_in[7];
    const float* eln1b = (const float*)d_in[8];
    const float* ef1w  = (const float*)d_in[9];
    const float* ef1b  = (const float*)d_in[10];
    const float* ef2w  = (const float*)d_in[11];
    const float* ef2b  = (const float*)d_in[12];
    const float* eln2g = (const float*)d_in[13];
    const float* eln2b = (const float*)d_in[14];
    const float* nfg   = (const float*)d_in[15];
    const float* nfb   = (const float*)d_in[16];
    const float* eoutw = (const float*)d_in[17];
    const float* eoutb = (const float*)d_in[18];
    const float* dsaqw = (const float*)d_in[19];
    const float* dsaqb = (const float*)d_in[20];
    const float* dsaow = (const float*)d_in[21];
    const float* dsaob = (const float*)d_in[22];
    const float* dcaqw = (const float*)d_in[23];
    const float* dcaqb = (const float*)d_in[24];
    const float* dcaow = (const float*)d_in[25];
    const float* dcaob = (const float*)d_in[26];
    const float* dln1g = (const float*)d_in[27];
    const float* dln1b = (const float*)d_in[28];
    const float* dln2g = (const float*)d_in[29];
    const float* dln2b = (const float*)d_in[30];
    const float* dln3g = (const float*)d_in[31];
    const float* dln3b = (const float*)d_in[32];
    const float* df1w  = (const float*)d_in[33];
    const float* df1b  = (const float*)d_in[34];
    const float* df2w  = (const float*)d_in[35];
    const float* df2b  = (const float*)d_in[36];
    float* out = (float*)d_out;

    float* ws = (float*)d_ws;
    float* pe     = ws;                       // 8192
    float* x      = pe + 8192;                // 1572864
    float* qkv    = x + 1572864;              // 4718592 (also reused as oproj output)
    float* scores = qkv + 4718592;            // 1179648
    float* attn   = scores + 1179648;         // 1572864
    float* mem    = attn + 1572864;           // 9216
    float* kmem   = mem + 9216;               // 36864
    float* vmem   = kmem + 36864;             // 36864
    float* yb     = qkv;                      // alias: Q/K/V dead after PV

    pe_k<<<16, 256, 0, stream>>>(pe);
    embed_k<<<NTOK, 256, 0, stream>>>(src, wemb, semb, pe, x);

    for (int l = 0; l < NLAY; ++l) {
        // QKV projection: (3072,512) @ (1536,512)^T
        gemm64<true><<<dim3(48, 24, 1), 256, 0, stream>>>(
            x, 512, 0, 0,
            eqkvw + (size_t)l * 786432, 512, 0, 0,
            qkv, 1536, 0, 0,
            512, eqkvb + l * 1536, 1.0f, 1);
        // scores = Q K^T / 16  : batched over (b,h)
        gemm64<true><<<dim3(3, 3, 32), 256, 0, stream>>>(
            qkv, 1536, 294912, 256,
            qkv + 512, 1536, 294912, 256,
            scores, 192, 73728, 36864,
            256, nullptr, 0.0625f, 2);
        enc_softmax<<<1536, 256, 0, stream>>>(scores);
        // attn = P @ V (NN)
        gemm64<false><<<dim3(3, 4, 32), 256, 0, stream>>>(
            scores, 192, 73728, 36864,
            qkv + 1024, 1536, 294912, 256,
            attn, 512, 98304, 256,
            192, nullptr, 1.0f, 2);
        // out-proj: (3072,512) @ (512,512)^T  -> yb (aliases qkv)
        gemm64<true><<<dim3(48, 8, 1), 256, 0, stream>>>(
            attn, 512, 0, 0,
            eow + (size_t)l * 262144, 512, 0, 0,
            yb, 512, 0, 0,
            512, eob + l * 512, 1.0f, 1);
        res_ln<<<NTOK, 256, 0, stream>>>(x, yb, eln1g + l * 512, eln1b + l * 512);
        enc_ffn_ln<<<NTOK, 256, 0, stream>>>(x, ef1w + l * 2048, ef1b + l * 4,
                                             ef2w + l * 2048, ef2b + l * 512,
                                             eln2g + l * 512, eln2b + l * 512);
    }

    eout_k<<<NTOK, 256, 0, stream>>>(x, nfg, nfb, eoutw, eoutb, src, mem, out);
    crosskv_k<<<48, 256, 0, stream>>>(mem, dcaqw, dcaqb, kmem, vmem);
    decoder_ar<<<BATCH, 64, 0, stream>>>(kmem, vmem,
        dsaqw, dsaqb, dsaow, dsaob, dcaqw, dcaqb, dcaow, dcaob,
        dln1g, dln1b, dln2g, dln2b, dln3g, dln3b,
        df1w, df1b, df2w, df2b, out);
}